// Round 18
// baseline (1692.804 us; speedup 1.0000x reference)
//
#include <hip/hip_runtime.h>

#define ATOM  14
#define BOND  3
#define INNER 20
#define HID   34
#define HIDP  36             // HID padded for LDS rows (and padded biases)
#define REC   20
#define OHID  25
#define NN    1048576
#define NE    983040
#define NG    16384

#define NB    512            // prep persistent grid
#define NT    256
#define GT    (NB*NT)        // 131072
#define SPAN  (NN/NB)        // 2048
#define SE    (SPAN/NT)      // 8

#define NB3   4096           // level blocks: 1 wave each, tree-bin = root & 4095
#define NT3   64
#define NG3   16             // 4-lane groups per wave
#define NBINS (NB3*32)       // bin = blk*32 + depth*2 + isLeaf  (131072)

__device__ __forceinline__ float leaky(float x) { return x >= 0.f ? x : 0.01f * x; }

// grid-wide barrier for prep only: device-scope fences (cross-XCD safe)
__device__ __forceinline__ void gbar_f(int* bar, int goal) {
    __syncthreads();
    if (threadIdx.x == 0) {
        __threadfence();
        __hip_atomic_fetch_add(bar, 1, __ATOMIC_RELEASE, __HIP_MEMORY_SCOPE_AGENT);
        while (__hip_atomic_load(bar, __ATOMIC_RELAXED, __HIP_MEMORY_SCOPE_AGENT) < goal)
            __builtin_amdgcn_s_sleep(32);
        __threadfence();
    }
    __syncthreads();
}

__global__ void k_pre(int* cnt_n, int* pnode, float* g, int* bin_cnt, int* totals, int* bars) {
    int tid = blockIdx.x * 256 + threadIdx.x;          // 262144 threads
    for (int i = tid; i < NN; i += 262144) { cnt_n[i] = 0; pnode[i] = i; }
    for (int i = tid; i < NG * REC; i += 262144) g[i] = 0.f;
    for (int i = tid; i < NBINS; i += 262144) bin_cnt[i] = 0;
    if (tid == 0) { totals[0] = 0; totals[16] = 0; }
    if (tid == 1) for (int k = 0; k < 32; ++k) bars[k] = 0;
}

// ---------------- prep: counts, root-chase, sort, CSR (5 barriers) ----------------
__global__ __launch_bounds__(NT) void k_prep(
    const int* __restrict__ parent, const int* __restrict__ child,
    const int* __restrict__ depth, const int* __restrict__ gid,
    const float* __restrict__ isr, const float* __restrict__ bond,
    int* cnt_n, int* pnode, int* r1, int* r2,
    int* K_s, int* cnt_s, int* row_ptr, int* adjc, float4* bond_s4,
    int* bin_cnt, int* bin_base, int* bin_cur,
    int* totals, int* bar)
{
    __shared__ int sh[NT];
    __shared__ int sbase_sh;
    const int t = threadIdx.x;
    const int tid = blockIdx.x * NT + t;
    int ep = 0;

    // P0: child counts + parent pointers
    for (int e = tid; e < NE; e += GT) {
        atomicAdd(&cnt_n[parent[e]], 1);
        pnode[child[e]] = parent[e];
    }
    gbar_f(bar, NB * ++ep);

    // P1: per-node root chase + bin key + histogram
    for (int i = tid; i < NN; i += GT) {
        int d = depth[i];
        int r = i;
        for (int s = 0; s < d; ++s) r = pnode[r];   // fixed-point safe at roots
        int K = (r & (NB3 - 1)) * 32 + d * 2 + (cnt_n[i] == 0 ? 1 : 0);
        K_s[i] = K;
        atomicAdd(&bin_cnt[K], 1);
    }
    gbar_f(bar, NB * ++ep);

    // P2: bin scan (orderless base): all 512 blocks, 256 bins each
    if (blockIdx.x < NBINS / NT) {
        int k0 = blockIdx.x * NT + t;
        int v = bin_cnt[k0];
        sh[t] = v;
        __syncthreads();
        for (int ofs = 1; ofs < NT; ofs <<= 1) {
            int x = (t >= ofs) ? sh[t - ofs] : 0;
            __syncthreads();
            sh[t] += x;
            __syncthreads();
        }
        if (t == NT - 1) sbase_sh = atomicAdd(&totals[0], sh[t]);
        __syncthreads();
        int b = sbase_sh + sh[t] - v;
        bin_base[k0] = b;
        bin_cur[k0] = b;
    }
    gbar_f(bar, NB * ++ep);

    // P3: scatter (counting sort); node_list aliases pnode (dead after P1)
    for (int i = tid; i < NN; i += GT) {
        int pos = atomicAdd(&bin_cur[K_s[i]], 1);
        pnode[pos] = i;                                 // node_list
        r1[i] = pos;                                    // inv
        r2[pos] = (isr[i] != 0.f) ? gid[i] : -1;        // groot_s
        cnt_s[pos] = cnt_n[i];
    }
    gbar_f(bar, NB * ++ep);

    // P4: row_ptr via span scan + orderless base; cnt_n reused as cur
    {
        int base0 = blockIdx.x * SPAN + t * SE;
        int v[SE]; int sum = 0;
        #pragma unroll
        for (int k = 0; k < SE; ++k) { v[k] = cnt_s[base0 + k]; sum += v[k]; }
        __syncthreads();
        sh[t] = sum;
        __syncthreads();
        for (int ofs = 1; ofs < NT; ofs <<= 1) {
            int x = (t >= ofs) ? sh[t - ofs] : 0;
            __syncthreads();
            sh[t] += x;
            __syncthreads();
        }
        if (t == NT - 1) sbase_sh = atomicAdd(&totals[16], sh[t]);
        __syncthreads();
        int run = sbase_sh + sh[t] - sum;
        #pragma unroll
        for (int k = 0; k < SE; ++k) { row_ptr[base0 + k] = run; cnt_n[base0 + k] = run; run += v[k]; }
    }
    gbar_f(bar, NB * ++ep);

    // P5: edge pass — adjc fill + per-child bond
    for (int e = tid; e < NE; e += GT) {
        int cpos = r1[child[e]];                        // inv
        int pp   = r1[parent[e]];
        int slot = atomicAdd(&cnt_n[pp], 1);            // cur
        adjc[slot] = cpos;
        bond_s4[cpos] = make_float4(bond[(size_t)e * BOND], bond[(size_t)e * BOND + 1],
                                    bond[(size_t)e * BOND + 2], 0.f);
    }
}

// ---------------- levels: 1 wave per tree-bin, shuffle MLP, NO barriers ----------------
__global__ __launch_bounds__(NT3) void k_levels(
    const float* __restrict__ atom,
    const int* __restrict__ node_list, const int* __restrict__ groot_s,
    const int* __restrict__ cnt_s, const int* __restrict__ row_ptr,
    const int* __restrict__ adjc, const float4* __restrict__ bond_s4,
    const int* __restrict__ bin_base, const int* __restrict__ bin_cnt,
    const float* __restrict__ iw, const float* __restrict__ ib,
    const float* __restrict__ nw1, const float* __restrict__ nb1,
    const float* __restrict__ nw2, const float* __restrict__ nb2,
    const float* __restrict__ l0w1, const float* __restrict__ l0b1,
    const float* __restrict__ l0w2, const float* __restrict__ l0b2,
    float* __restrict__ g, float* msg_s)
{
    __shared__ float lw1[34 * HIDP];     // net_w1  [34][36]
    __shared__ float lw2[HID * REC];     // net_w2  [34][20]
    __shared__ float liw[23 * REC];      // inner_w [23][20]
    __shared__ float zw1[ATOM * HIDP];   // net0_w1 [14][36]
    __shared__ float zw2[HID * REC];     // net0_w2 [34][20]
    __shared__ float lb1[HIDP], zb1[HIDP];   // padded: h>=34 reads 0
    __shared__ float lb2[REC], lbi[INNER], zb2[REC];

    const int t = threadIdx.x;
    const int b = blockIdx.x;
    const int slot = t >> 2;             // node-group 0..15
    const int j = t & 3;                 // lane slice 0..3

    for (int idx = t; idx < 34 * HIDP; idx += NT3) {
        int r = idx / HIDP, c = idx - r * HIDP;
        lw1[idx] = (c < HID) ? nw1[r * HID + c] : 0.f;
    }
    for (int idx = t; idx < HID * REC; idx += NT3) { lw2[idx] = nw2[idx]; zw2[idx] = l0w2[idx]; }
    for (int idx = t; idx < 23 * REC; idx += NT3) liw[idx] = iw[idx];
    for (int idx = t; idx < ATOM * HIDP; idx += NT3) {
        int r = idx / HIDP, c = idx - r * HIDP;
        zw1[idx] = (c < HID) ? l0w1[r * HID + c] : 0.f;
    }
    if (t < HIDP) { lb1[t] = (t < HID) ? nb1[t] : 0.f; zb1[t] = (t < HID) ? l0b1[t] : 0.f; }
    if (t < REC)  { lb2[t] = nb2[t]; zb2[t] = l0b2[t]; }
    if (t < INNER) lbi[t] = ib[t];
    __syncthreads();

    for (int d = 15; d >= 0; --d) {
        // ---- internal nodes (bin b*32 + d*2) ----
        {
            int K = b * 32 + d * 2;
            int base = bin_base[K], n0 = bin_cnt[K];
            for (int idx = slot; idx < n0; idx += NG3) {
                int pos = base + idx;
                int n   = cnt_s[pos];
                int i   = node_list[pos];
                int gr  = groot_s[pos];
                int rp0 = row_ptr[pos];
                // atom fragment: lane j holds atom[4j..4j+3] (guarded)
                const float* ar = atom + (size_t)i * ATOM;
                float aa[4];
                #pragma unroll
                for (int u = 0; u < 4; ++u) { int k = 4*j + u; aa[u] = (k < ATOM) ? ar[k] : 0.f; }
                // isum fragment: lane j sums msg slice [5j, 5j+5)
                float ss[5] = {0.f, 0.f, 0.f, 0.f, 0.f};
                for (int r = rp0; r < rp0 + n; ++r) {
                    const float* mp = msg_s + (size_t)adjc[r] * REC + 5*j;
                    ss[0] += mp[0]; ss[1] += mp[1]; ss[2] += mp[2]; ss[3] += mp[3]; ss[4] += mp[4];
                }
                // phase 1: hidden slice h = 9j..9j+8 (padded weights -> no guards)
                float acc[9];
                #pragma unroll
                for (int u = 0; u < 9; ++u) acc[u] = lb1[9*j + u];
                #pragma unroll
                for (int k = 0; k < ATOM + INNER; ++k) {
                    float xk = (k < ATOM) ? __shfl(aa[k & 3], k >> 2, 4)
                                          : __shfl(ss[(k - ATOM) % 5], (k - ATOM) / 5, 4);
                    #pragma unroll
                    for (int u = 0; u < 9; ++u) acc[u] += xk * lw1[k * HIDP + 9*j + u];
                }
                #pragma unroll
                for (int u = 0; u < 9; ++u) acc[u] = leaky(acc[u]);
                // phase 2: output slice 5j..5j+4
                float o[5];
                #pragma unroll
                for (int u = 0; u < 5; ++u) o[u] = lb2[5*j + u];
                #pragma unroll
                for (int k = 0; k < HID; ++k) {
                    float hk = __shfl(acc[k % 9], k / 9, 4);
                    #pragma unroll
                    for (int u = 0; u < 5; ++u) o[u] += hk * lw2[k * REC + 5*j + u];
                }
                #pragma unroll
                for (int u = 0; u < 5; ++u) o[u] = leaky(o[u]);
                // emit
                if (gr >= 0) {
                    #pragma unroll
                    for (int u = 0; u < 5; ++u) atomicAdd(&g[(size_t)gr * REC + 5*j + u], o[u]);
                } else {
                    float4 b4 = bond_s4[pos];
                    float m[5];
                    #pragma unroll
                    for (int u = 0; u < 5; ++u)
                        m[u] = lbi[5*j + u] + b4.x * liw[0 * INNER + 5*j + u]
                             + b4.y * liw[1 * INNER + 5*j + u] + b4.z * liw[2 * INNER + 5*j + u];
                    #pragma unroll
                    for (int k = 0; k < REC; ++k) {
                        float ok = __shfl(o[k % 5], k / 5, 4);
                        #pragma unroll
                        for (int u = 0; u < 5; ++u) m[u] += ok * liw[(BOND + k) * INNER + 5*j + u];
                    }
                    float* mp = msg_s + (size_t)pos * REC + 5*j;
                    #pragma unroll
                    for (int u = 0; u < 5; ++u) mp[u] = leaky(m[u]);
                }
            }
        }
        // ---- leaves (bin b*32 + d*2 + 1) ----
        {
            int K = b * 32 + d * 2 + 1;
            int base = bin_base[K], n1 = bin_cnt[K];
            for (int idx = slot; idx < n1; idx += NG3) {
                int pos = base + idx;
                int i  = node_list[pos];
                int gr = groot_s[pos];
                const float* ar = atom + (size_t)i * ATOM;
                float aa[4];
                #pragma unroll
                for (int u = 0; u < 4; ++u) { int k = 4*j + u; aa[u] = (k < ATOM) ? ar[k] : 0.f; }
                float acc[9];
                #pragma unroll
                for (int u = 0; u < 9; ++u) acc[u] = zb1[9*j + u];
                #pragma unroll
                for (int k = 0; k < ATOM; ++k) {
                    float xk = __shfl(aa[k & 3], k >> 2, 4);
                    #pragma unroll
                    for (int u = 0; u < 9; ++u) acc[u] += xk * zw1[k * HIDP + 9*j + u];
                }
                #pragma unroll
                for (int u = 0; u < 9; ++u) acc[u] = leaky(acc[u]);
                float o[5];
                #pragma unroll
                for (int u = 0; u < 5; ++u) o[u] = zb2[5*j + u];
                #pragma unroll
                for (int k = 0; k < HID; ++k) {
                    float hk = __shfl(acc[k % 9], k / 9, 4);
                    #pragma unroll
                    for (int u = 0; u < 5; ++u) o[u] += hk * zw2[k * REC + 5*j + u];
                }
                #pragma unroll
                for (int u = 0; u < 5; ++u) o[u] = leaky(o[u]);
                if (gr >= 0) {
                    #pragma unroll
                    for (int u = 0; u < 5; ++u) atomicAdd(&g[(size_t)gr * REC + 5*j + u], o[u]);
                } else {
                    float4 b4 = bond_s4[pos];
                    float m[5];
                    #pragma unroll
                    for (int u = 0; u < 5; ++u)
                        m[u] = lbi[5*j + u] + b4.x * liw[0 * INNER + 5*j + u]
                             + b4.y * liw[1 * INNER + 5*j + u] + b4.z * liw[2 * INNER + 5*j + u];
                    #pragma unroll
                    for (int k = 0; k < REC; ++k) {
                        float ok = __shfl(o[k % 5], k / 5, 4);
                        #pragma unroll
                        for (int u = 0; u < 5; ++u) m[u] += ok * liw[(BOND + k) * INNER + 5*j + u];
                    }
                    float* mp = msg_s + (size_t)pos * REC + 5*j;
                    #pragma unroll
                    for (int u = 0; u < 5; ++u) mp[u] = leaky(m[u]);
                }
            }
        }
        // no barrier: producer and consumer are the same wave
    }
}

// ---------------- readout ----------------
__global__ void k_out(const float* __restrict__ g,
                      const float* __restrict__ w1, const float* __restrict__ b1,
                      const float* __restrict__ w2, const float* __restrict__ b2,
                      float* __restrict__ out) {
    int t = blockIdx.x * 256 + threadIdx.x;
    if (t >= NG) return;
    const float* gv = g + (size_t)t * REC;
    float gl[REC];
    #pragma unroll
    for (int k = 0; k < REC; ++k) gl[k] = gv[k];
    float acc = b2[0];
    for (int j = 0; j < OHID; ++j) {
        float s = b1[j];
        #pragma unroll
        for (int k = 0; k < REC; ++k) s += gl[k] * w1[k * OHID + j];
        acc += tanhf(s) * w2[j];
    }
    out[t] = acc;
}

extern "C" void kernel_launch(void* const* d_in, const int* in_sizes, int n_in,
                              void* d_out, int out_size, void* d_ws, size_t ws_size,
                              hipStream_t stream) {
    const float* atom    = (const float*)d_in[0];
    const float* bond    = (const float*)d_in[1];
    const int*   parent  = (const int*)d_in[2];
    const int*   child   = (const int*)d_in[3];
    const int*   depth   = (const int*)d_in[4];
    const int*   gid     = (const int*)d_in[5];
    const float* isr     = (const float*)d_in[6];
    const float* inner_w = (const float*)d_in[7];
    const float* inner_b = (const float*)d_in[8];
    const float* net_w1  = (const float*)d_in[9];
    const float* net_b1  = (const float*)d_in[10];
    const float* net_w2  = (const float*)d_in[11];
    const float* net_b2  = (const float*)d_in[12];
    const float* net0_w1 = (const float*)d_in[13];
    const float* net0_b1 = (const float*)d_in[14];
    const float* net0_w2 = (const float*)d_in[15];
    const float* net0_b2 = (const float*)d_in[16];
    const float* out_w1  = (const float*)d_in[17];
    const float* out_b1  = (const float*)d_in[18];
    const float* out_w2  = (const float*)d_in[19];
    const float* out_b2  = (const float*)d_in[20];
    float* out = (float*)d_out;

    char* ws = (char*)d_ws;
    size_t o = 0;
    float* msg_s    = (float*)(ws + o);  o += (size_t)NN * REC * 4;    // 83.9 MB
    float4* bond_s4 = (float4*)(ws + o); o += (size_t)NN * 16;         // 16.8 MB
    float* g        = (float*)(ws + o);  o += (size_t)NG * REC * 4;    // 1.3 MB
    int* adjc       = (int*)(ws + o);    o += (size_t)NE * 4;          // 3.9 MB
    int* cnt_n      = (int*)(ws + o);    o += (size_t)NN * 4;          // 4.2 MB (also cur)
    int* pnode      = (int*)(ws + o);    o += (size_t)NN * 4;          // 4.2 MB (also node_list)
    int* r1         = (int*)(ws + o);    o += (size_t)NN * 4;          // 4.2 MB (inv)
    int* r2         = (int*)(ws + o);    o += (size_t)NN * 4;          // 4.2 MB (groot_s)
    int* K_s        = (int*)(ws + o);    o += (size_t)NN * 4;          // 4.2 MB
    int* cnt_s      = (int*)(ws + o);    o += (size_t)NN * 4;          // 4.2 MB
    int* row_ptr    = (int*)(ws + o);    o += (size_t)NN * 4;          // 4.2 MB
    int* bin_cnt    = (int*)(ws + o);    o += (size_t)NBINS * 4;       // 512 KB
    int* bin_base   = (int*)(ws + o);    o += (size_t)NBINS * 4;       // 512 KB
    int* bin_cur    = (int*)(ws + o);    o += (size_t)NBINS * 4;       // 512 KB
    int* totals     = (int*)(ws + o);    o += 32 * 4;
    int* bars       = (int*)(ws + o);    o += 32 * 4;
    // total ~137 MB

    k_pre<<<1024, 256, 0, stream>>>(cnt_n, pnode, g, bin_cnt, totals, bars);
    k_prep<<<NB, NT, 0, stream>>>(parent, child, depth, gid, isr, bond,
                                  cnt_n, pnode, r1, r2, K_s, cnt_s, row_ptr,
                                  adjc, bond_s4, bin_cnt, bin_base, bin_cur,
                                  totals, bars);
    k_levels<<<NB3, NT3, 0, stream>>>(atom, pnode /*node_list*/, r2 /*groot_s*/,
                                      cnt_s, row_ptr, adjc, bond_s4,
                                      bin_base, bin_cnt,
                                      inner_w, inner_b, net_w1, net_b1, net_w2, net_b2,
                                      net0_w1, net0_b1, net0_w2, net0_b2,
                                      g, msg_s);
    k_out<<<(NG + 255) / 256, 256, 0, stream>>>(g, out_w1, out_b1, out_w2, out_b2, out);
}

// Round 19
// 956.711 us; speedup vs baseline: 1.7694x; 1.7694x over previous
//
#include <hip/hip_runtime.h>

#define ATOM  14
#define BOND  3
#define INNER 20
#define HID   34
#define HIDP  36             // HID padded for LDS rows
#define REC   20
#define OHID  25
#define NN    1048576
#define NE    983040
#define NG    16384

#define NB    512            // prep persistent grid
#define NT    256
#define GT    (NB*NT)        // 131072
#define SPAN  (NN/NB)        // 2048
#define SE    (SPAN/NT)      // 8

#define NB2   1024           // level blocks (independent tree-bins)
#define NT2   256            // 4 waves
#define NGRP  (NT2/4)        // 64 node-groups (4 lanes each) per block
#define SSTR  (NGRP+1)       // 65: stride-padded staging (bank = (k+slot)%32)
#define NBINS (NB2*32)       // bin = blk*32 + depth*2 + isLeaf

__device__ __forceinline__ float leaky(float x) { return x >= 0.f ? x : 0.01f * x; }

__device__ __forceinline__ void wsync() {
    __builtin_amdgcn_wave_barrier();
    __builtin_amdgcn_sched_barrier(0);
}

// grid-wide barrier for prep only: device-scope fences (cross-XCD safe)
__device__ __forceinline__ void gbar_f(int* bar, int goal) {
    __syncthreads();
    if (threadIdx.x == 0) {
        __threadfence();
        __hip_atomic_fetch_add(bar, 1, __ATOMIC_RELEASE, __HIP_MEMORY_SCOPE_AGENT);
        while (__hip_atomic_load(bar, __ATOMIC_RELAXED, __HIP_MEMORY_SCOPE_AGENT) < goal)
            __builtin_amdgcn_s_sleep(32);
        __threadfence();
    }
    __syncthreads();
}

__global__ void k_pre(int* cnt_n, int* pnode, float* g, int* bin_cnt, int* totals, int* bars) {
    int tid = blockIdx.x * 256 + threadIdx.x;          // 262144 threads
    for (int i = tid; i < NN; i += 262144) { cnt_n[i] = 0; pnode[i] = i; }
    for (int i = tid; i < NG * REC; i += 262144) g[i] = 0.f;
    for (int i = tid; i < NBINS; i += 262144) bin_cnt[i] = 0;
    if (tid == 0) { totals[0] = 0; totals[16] = 0; }
    if (tid == 1) for (int k = 0; k < 32; ++k) bars[k] = 0;
}

// ---------------- prep: counts, root-chase, sort, CSR (5 barriers) ----------------
__global__ __launch_bounds__(NT) void k_prep(
    const int* __restrict__ parent, const int* __restrict__ child,
    const int* __restrict__ depth, const int* __restrict__ gid,
    const float* __restrict__ isr, const float* __restrict__ bond,
    int* cnt_n, int* pnode, int* r1, int* r2,
    int* K_s, int* cnt_s, int* row_ptr, int* adjc, float4* bond_s4,
    int* bin_cnt, int* bin_base, int* bin_cur,
    int* totals, int* bar)
{
    __shared__ int sh[NT];
    __shared__ int sbase_sh;
    const int t = threadIdx.x;
    const int tid = blockIdx.x * NT + t;
    int ep = 0;

    // P0: child counts + parent pointers
    for (int e = tid; e < NE; e += GT) {
        atomicAdd(&cnt_n[parent[e]], 1);
        pnode[child[e]] = parent[e];
    }
    gbar_f(bar, NB * ++ep);

    // P1: per-node root chase + bin key + histogram
    for (int i = tid; i < NN; i += GT) {
        int d = depth[i];
        int r = i;
        for (int s = 0; s < d; ++s) r = pnode[r];   // fixed-point safe at roots
        int K = (r & (NB2 - 1)) * 32 + d * 2 + (cnt_n[i] == 0 ? 1 : 0);
        K_s[i] = K;
        atomicAdd(&bin_cnt[K], 1);
    }
    gbar_f(bar, NB * ++ep);

    // P2: bin scan (orderless base): blocks 0..127, 256 bins each
    if (blockIdx.x < NBINS / NT) {
        int k0 = blockIdx.x * NT + t;
        int v = bin_cnt[k0];
        sh[t] = v;
        __syncthreads();
        for (int ofs = 1; ofs < NT; ofs <<= 1) {
            int x = (t >= ofs) ? sh[t - ofs] : 0;
            __syncthreads();
            sh[t] += x;
            __syncthreads();
        }
        if (t == NT - 1) sbase_sh = atomicAdd(&totals[0], sh[t]);
        __syncthreads();
        int b = sbase_sh + sh[t] - v;
        bin_base[k0] = b;
        bin_cur[k0] = b;
    }
    gbar_f(bar, NB * ++ep);

    // P3: scatter (counting sort); node_list aliases pnode (dead after P1)
    for (int i = tid; i < NN; i += GT) {
        int pos = atomicAdd(&bin_cur[K_s[i]], 1);
        pnode[pos] = i;                                 // node_list
        r1[i] = pos;                                    // inv
        r2[pos] = (isr[i] != 0.f) ? gid[i] : -1;        // groot_s
        cnt_s[pos] = cnt_n[i];
    }
    gbar_f(bar, NB * ++ep);

    // P4: row_ptr via span scan + orderless base; cnt_n reused as cur
    {
        int base0 = blockIdx.x * SPAN + t * SE;
        int v[SE]; int sum = 0;
        #pragma unroll
        for (int k = 0; k < SE; ++k) { v[k] = cnt_s[base0 + k]; sum += v[k]; }
        __syncthreads();
        sh[t] = sum;
        __syncthreads();
        for (int ofs = 1; ofs < NT; ofs <<= 1) {
            int x = (t >= ofs) ? sh[t - ofs] : 0;
            __syncthreads();
            sh[t] += x;
            __syncthreads();
        }
        if (t == NT - 1) sbase_sh = atomicAdd(&totals[16], sh[t]);
        __syncthreads();
        int run = sbase_sh + sh[t] - sum;
        #pragma unroll
        for (int k = 0; k < SE; ++k) { row_ptr[base0 + k] = run; cnt_n[base0 + k] = run; run += v[k]; }
    }
    gbar_f(bar, NB * ++ep);

    // P5: edge pass — adjc fill + per-child bond
    for (int e = tid; e < NE; e += GT) {
        int cpos = r1[child[e]];                        // inv
        int pp   = r1[parent[e]];
        int slot = atomicAdd(&cnt_n[pp], 1);            // cur
        adjc[slot] = cpos;
        bond_s4[cpos] = make_float4(bond[(size_t)e * BOND], bond[(size_t)e * BOND + 1],
                                    bond[(size_t)e * BOND + 2], 0.f);
    }
}

// cooperative MLP phases 1-2 (x pre-staged in xs column `slot`): lane j owns
// hidden units 9j..9j+8 and outputs 5j..5j+4. Result: o[5] + os column.
__device__ __forceinline__ void coop_mlp(int slot, int j, int KN,
                                         const float* xs, float* hs, float* os,
                                         const float* w1, const float* b1,
                                         const float* w2, const float* b2,
                                         float* o)
{
    wsync();                       // xs writes (all lanes) before xs reads
    float acc[9];
    #pragma unroll
    for (int u = 0; u < 9; ++u) { int h = 9*j + u; acc[u] = (h < HID) ? b1[h] : 0.f; }
    #pragma unroll 2
    for (int k = 0; k < KN; ++k) {
        float xk = xs[k * SSTR + slot];
        #pragma unroll
        for (int u = 0; u < 9; ++u) { int h = 9*j + u; if (h < HID) acc[u] += xk * w1[k * HIDP + h]; }
    }
    #pragma unroll
    for (int u = 0; u < 9; ++u) { int h = 9*j + u; if (h < HID) hs[h * SSTR + slot] = leaky(acc[u]); }
    wsync();                       // hs writes before hs reads
    #pragma unroll
    for (int u = 0; u < 5; ++u) o[u] = b2[5*j + u];
    #pragma unroll 2
    for (int k = 0; k < HID; ++k) {
        float hk = hs[k * SSTR + slot];
        #pragma unroll
        for (int u = 0; u < 5; ++u) o[u] += hk * w2[k * REC + 5*j + u];
    }
    #pragma unroll
    for (int u = 0; u < 5; ++u) { o[u] = leaky(o[u]); os[(5*j + u) * SSTR + slot] = o[u]; }
    wsync();                       // os writes before os reads (msg phase)
}

// ---------------- levels: 4 lanes per node, stride-padded staging ----------------
__global__ __launch_bounds__(NT2) void k_levels(
    const float* __restrict__ atom,
    const int* __restrict__ node_list, const int* __restrict__ groot_s,
    const int* __restrict__ cnt_s, const int* __restrict__ row_ptr,
    const int* __restrict__ adjc, const float4* __restrict__ bond_s4,
    const int* __restrict__ bin_base, const int* __restrict__ bin_cnt,
    const float* __restrict__ iw, const float* __restrict__ ib,
    const float* __restrict__ nw1, const float* __restrict__ nb1,
    const float* __restrict__ nw2, const float* __restrict__ nb2,
    const float* __restrict__ l0w1, const float* __restrict__ l0b1,
    const float* __restrict__ l0w2, const float* __restrict__ l0b2,
    float* __restrict__ g, float* __restrict__ msg_s)
{
    __shared__ float lw1[34 * HIDP];     // net_w1  [34][36]
    __shared__ float lw2[HID * REC];     // net_w2  [34][20]
    __shared__ float liw[23 * REC];      // inner_w [23][20]
    __shared__ float zw1[ATOM * HIDP];   // net0_w1 [14][36]
    __shared__ float zw2[HID * REC];     // net0_w2 [34][20]
    __shared__ float lb1[HID], lb2[REC], lbi[INNER], zb1[HID], zb2[REC];
    __shared__ float xs[34 * SSTR];      // x staging   [34][65]
    __shared__ float hs[34 * SSTR];      // hid staging [34][65]
    __shared__ float os[20 * SSTR];      // out staging [20][65]

    const int t = threadIdx.x;
    const int b = blockIdx.x;
    const int slot = t >> 2;             // node-group 0..63
    const int j = t & 3;                 // lane slice 0..3

    for (int idx = t; idx < 34 * HIDP; idx += NT2) {
        int r = idx / HIDP, c = idx - r * HIDP;
        lw1[idx] = (c < HID) ? nw1[r * HID + c] : 0.f;
    }
    for (int idx = t; idx < HID * REC; idx += NT2) { lw2[idx] = nw2[idx]; zw2[idx] = l0w2[idx]; }
    for (int idx = t; idx < 23 * REC; idx += NT2) liw[idx] = iw[idx];
    for (int idx = t; idx < ATOM * HIDP; idx += NT2) {
        int r = idx / HIDP, c = idx - r * HIDP;
        zw1[idx] = (c < HID) ? l0w1[r * HID + c] : 0.f;
    }
    if (t < HID) { lb1[t] = nb1[t]; zb1[t] = l0b1[t]; }
    else if (t >= 64 && t < 64 + REC) { lb2[t - 64] = nb2[t - 64]; zb2[t - 64] = l0b2[t - 64]; }
    if (t >= 96 && t < 96 + INNER) lbi[t - 96] = ib[t - 96];
    __syncthreads();

    for (int d = 15; d >= 0; --d) {
        // ---- internal nodes (bin b*32 + d*2) ----
        {
            int K = b * 32 + d * 2;
            int base = bin_base[K], n0 = bin_cnt[K];
            for (int idx = slot; idx < n0; idx += NGRP) {
                int pos = base + idx;
                int n   = cnt_s[pos];
                int i   = node_list[pos];
                int gr  = groot_s[pos];
                int rp0 = row_ptr[pos];
                // gather: lane j sums msg slice q in [5j,5j+5)
                float s0 = 0.f, s1 = 0.f, s2 = 0.f, s3 = 0.f, s4 = 0.f;
                for (int r = rp0; r < rp0 + n; ++r) {
                    const float* mp = msg_s + (size_t)adjc[r] * REC + 5*j;
                    s0 += mp[0]; s1 += mp[1]; s2 += mp[2]; s3 += mp[3]; s4 += mp[4];
                }
                // stage x = [atom, isum]: lane j writes atom[4j..] and isum slice
                const float* ar = atom + (size_t)i * ATOM;
                #pragma unroll
                for (int u = 0; u < 4; ++u) { int k = 4*j + u; if (k < ATOM) xs[k * SSTR + slot] = ar[k]; }
                xs[(ATOM + 5*j + 0) * SSTR + slot] = s0;
                xs[(ATOM + 5*j + 1) * SSTR + slot] = s1;
                xs[(ATOM + 5*j + 2) * SSTR + slot] = s2;
                xs[(ATOM + 5*j + 3) * SSTR + slot] = s3;
                xs[(ATOM + 5*j + 4) * SSTR + slot] = s4;
                float o[5];
                coop_mlp(slot, j, ATOM + INNER, xs, hs, os, lw1, lb1, lw2, lb2, o);
                if (gr >= 0) {
                    #pragma unroll
                    for (int u = 0; u < 5; ++u) atomicAdd(&g[(size_t)gr * REC + 5*j + u], o[u]);
                } else {
                    float4 b4 = bond_s4[pos];
                    float m[5];
                    #pragma unroll
                    for (int u = 0; u < 5; ++u)
                        m[u] = lbi[5*j + u] + b4.x * liw[0 * INNER + 5*j + u]
                             + b4.y * liw[1 * INNER + 5*j + u] + b4.z * liw[2 * INNER + 5*j + u];
                    #pragma unroll 2
                    for (int k = 0; k < REC; ++k) {
                        float ok = os[k * SSTR + slot];
                        #pragma unroll
                        for (int u = 0; u < 5; ++u) m[u] += ok * liw[(BOND + k) * INNER + 5*j + u];
                    }
                    #pragma unroll
                    for (int u = 0; u < 5; ++u) msg_s[(size_t)pos * REC + 5*j + u] = leaky(m[u]);
                }
            }
        }
        // ---- leaves (bin b*32 + d*2 + 1) ----
        {
            int K = b * 32 + d * 2 + 1;
            int base = bin_base[K], n1 = bin_cnt[K];
            for (int idx = slot; idx < n1; idx += NGRP) {
                int pos = base + idx;
                int i  = node_list[pos];
                int gr = groot_s[pos];
                const float* ar = atom + (size_t)i * ATOM;
                #pragma unroll
                for (int u = 0; u < 4; ++u) { int k = 4*j + u; if (k < ATOM) xs[k * SSTR + slot] = ar[k]; }
                float o[5];
                coop_mlp(slot, j, ATOM, xs, hs, os, zw1, zb1, zw2, zb2, o);
                if (gr >= 0) {
                    #pragma unroll
                    for (int u = 0; u < 5; ++u) atomicAdd(&g[(size_t)gr * REC + 5*j + u], o[u]);
                } else {
                    float4 b4 = bond_s4[pos];
                    float m[5];
                    #pragma unroll
                    for (int u = 0; u < 5; ++u)
                        m[u] = lbi[5*j + u] + b4.x * liw[0 * INNER + 5*j + u]
                             + b4.y * liw[1 * INNER + 5*j + u] + b4.z * liw[2 * INNER + 5*j + u];
                    #pragma unroll 2
                    for (int k = 0; k < REC; ++k) {
                        float ok = os[k * SSTR + slot];
                        #pragma unroll
                        for (int u = 0; u < 5; ++u) m[u] += ok * liw[(BOND + k) * INNER + 5*j + u];
                    }
                    #pragma unroll
                    for (int u = 0; u < 5; ++u) msg_s[(size_t)pos * REC + 5*j + u] = leaky(m[u]);
                }
            }
        }
        // block-local level barrier (msg producer->consumer across waves)
        __threadfence_block();
        __syncthreads();
    }
}

// ---------------- readout ----------------
__global__ void k_out(const float* __restrict__ g,
                      const float* __restrict__ w1, const float* __restrict__ b1,
                      const float* __restrict__ w2, const float* __restrict__ b2,
                      float* __restrict__ out) {
    int t = blockIdx.x * 256 + threadIdx.x;
    if (t >= NG) return;
    const float* gv = g + (size_t)t * REC;
    float gl[REC];
    #pragma unroll
    for (int k = 0; k < REC; ++k) gl[k] = gv[k];
    float acc = b2[0];
    for (int j = 0; j < OHID; ++j) {
        float s = b1[j];
        #pragma unroll
        for (int k = 0; k < REC; ++k) s += gl[k] * w1[k * OHID + j];
        acc += tanhf(s) * w2[j];
    }
    out[t] = acc;
}

extern "C" void kernel_launch(void* const* d_in, const int* in_sizes, int n_in,
                              void* d_out, int out_size, void* d_ws, size_t ws_size,
                              hipStream_t stream) {
    const float* atom    = (const float*)d_in[0];
    const float* bond    = (const float*)d_in[1];
    const int*   parent  = (const int*)d_in[2];
    const int*   child   = (const int*)d_in[3];
    const int*   depth   = (const int*)d_in[4];
    const int*   gid     = (const int*)d_in[5];
    const float* isr     = (const float*)d_in[6];
    const float* inner_w = (const float*)d_in[7];
    const float* inner_b = (const float*)d_in[8];
    const float* net_w1  = (const float*)d_in[9];
    const float* net_b1  = (const float*)d_in[10];
    const float* net_w2  = (const float*)d_in[11];
    const float* net_b2  = (const float*)d_in[12];
    const float* net0_w1 = (const float*)d_in[13];
    const float* net0_b1 = (const float*)d_in[14];
    const float* net0_w2 = (const float*)d_in[15];
    const float* net0_b2 = (const float*)d_in[16];
    const float* out_w1  = (const float*)d_in[17];
    const float* out_b1  = (const float*)d_in[18];
    const float* out_w2  = (const float*)d_in[19];
    const float* out_b2  = (const float*)d_in[20];
    float* out = (float*)d_out;

    char* ws = (char*)d_ws;
    size_t o = 0;
    float* msg_s    = (float*)(ws + o);  o += (size_t)NN * REC * 4;    // 83.9 MB
    float4* bond_s4 = (float4*)(ws + o); o += (size_t)NN * 16;         // 16.8 MB
    float* g        = (float*)(ws + o);  o += (size_t)NG * REC * 4;    // 1.3 MB
    int* adjc       = (int*)(ws + o);    o += (size_t)NE * 4;          // 3.9 MB
    int* cnt_n      = (int*)(ws + o);    o += (size_t)NN * 4;          // 4.2 MB (also cur)
    int* pnode      = (int*)(ws + o);    o += (size_t)NN * 4;          // 4.2 MB (also node_list)
    int* r1         = (int*)(ws + o);    o += (size_t)NN * 4;          // 4.2 MB (inv)
    int* r2         = (int*)(ws + o);    o += (size_t)NN * 4;          // 4.2 MB (groot_s)
    int* K_s        = (int*)(ws + o);    o += (size_t)NN * 4;          // 4.2 MB
    int* cnt_s      = (int*)(ws + o);    o += (size_t)NN * 4;          // 4.2 MB
    int* row_ptr    = (int*)(ws + o);    o += (size_t)NN * 4;          // 4.2 MB
    int* bin_cnt    = (int*)(ws + o);    o += (size_t)NBINS * 4;       // 128 KB
    int* bin_base   = (int*)(ws + o);    o += (size_t)NBINS * 4;       // 128 KB
    int* bin_cur    = (int*)(ws + o);    o += (size_t)NBINS * 4;       // 128 KB
    int* totals     = (int*)(ws + o);    o += 32 * 4;
    int* bars       = (int*)(ws + o);    o += 32 * 4;
    // total ~136 MB

    k_pre<<<1024, 256, 0, stream>>>(cnt_n, pnode, g, bin_cnt, totals, bars);
    k_prep<<<NB, NT, 0, stream>>>(parent, child, depth, gid, isr, bond,
                                  cnt_n, pnode, r1, r2, K_s, cnt_s, row_ptr,
                                  adjc, bond_s4, bin_cnt, bin_base, bin_cur,
                                  totals, bars);
    k_levels<<<NB2, NT2, 0, stream>>>(atom, pnode /*node_list*/, r2 /*groot_s*/,
                                      cnt_s, row_ptr, adjc, bond_s4,
                                      bin_base, bin_cnt,
                                      inner_w, inner_b, net_w1, net_b1, net_w2, net_b2,
                                      net0_w1, net0_b1, net0_w2, net0_b2,
                                      g, msg_s);
    k_out<<<(NG + 255) / 256, 256, 0, stream>>>(g, out_w1, out_b1, out_w2, out_b2, out);
}

// Round 20
// 951.681 us; speedup vs baseline: 1.7788x; 1.0053x over previous
//
#include <hip/hip_runtime.h>

#define ATOM  14
#define BOND  3
#define INNER 20
#define HID   34
#define HIDP  36             // HID padded for LDS rows
#define REC   20
#define OHID  25
#define NN    1048576
#define NE    983040
#define NG    16384

#define NB    512            // prep persistent grid
#define NT    256
#define GT    (NB*NT)        // 131072
#define SPAN  (NN/NB)        // 2048
#define SE    (SPAN/NT)      // 8

#define NB2   1024           // level blocks (independent tree-bins)
#define NT2   256            // 4 waves
#define NGRP  (NT2/4)        // 64 node-groups (4 lanes each) per block
#define SSTR  (NGRP+1)       // 65: stride-padded staging
#define NBINS (NB2*32)       // bin = blk*32 + depth*2 + isLeaf

__device__ __forceinline__ float leaky(float x) { return x >= 0.f ? x : 0.01f * x; }

__device__ __forceinline__ void wsync() {
    __builtin_amdgcn_wave_barrier();
    __builtin_amdgcn_sched_barrier(0);
}

// grid-wide barrier for prep only: device-scope fences (cross-XCD safe)
__device__ __forceinline__ void gbar_f(int* bar, int goal) {
    __syncthreads();
    if (threadIdx.x == 0) {
        __threadfence();
        __hip_atomic_fetch_add(bar, 1, __ATOMIC_RELEASE, __HIP_MEMORY_SCOPE_AGENT);
        while (__hip_atomic_load(bar, __ATOMIC_RELAXED, __HIP_MEMORY_SCOPE_AGENT) < goal)
            __builtin_amdgcn_s_sleep(32);
        __threadfence();
    }
    __syncthreads();
}

__global__ void k_pre(int* cnt_n, int2* pnode2, float* g, int* bin_cnt, int* totals, int* bars) {
    int tid = blockIdx.x * 256 + threadIdx.x;          // 262144 threads
    for (int i = tid; i < NN; i += 262144) { cnt_n[i] = 0; pnode2[i] = make_int2(i, -1); }
    for (int i = tid; i < NG * REC; i += 262144) g[i] = 0.f;
    for (int i = tid; i < NBINS; i += 262144) bin_cnt[i] = 0;
    if (tid == 0) { totals[0] = 0; totals[16] = 0; }
    if (tid == 1) for (int k = 0; k < 32; ++k) bars[k] = 0;
}

// ---------------- prep: counts, root-chase, sort (packed), CSR ----------------
__global__ __launch_bounds__(NT) void k_prep(
    const int* __restrict__ parent, const int* __restrict__ child,
    const int* __restrict__ depth, const int* __restrict__ gid,
    const float* __restrict__ isr,
    int* cnt_n, int2* pnode2, int* inv, int* K_s,
    int4* nodeinfo, int* row_ptr, int* adjc,
    int* bin_cnt, int* bin_base, int* bin_cur,
    int* totals, int* bar)
{
    __shared__ int sh[NT];
    __shared__ int sbase_sh;
    const int t = threadIdx.x;
    const int tid = blockIdx.x * NT + t;
    int ep = 0;

    // P0: child counts + packed (parent, edge-id) per child
    for (int e = tid; e < NE; e += GT) {
        atomicAdd(&cnt_n[parent[e]], 1);
        pnode2[child[e]] = make_int2(parent[e], e);
    }
    gbar_f(bar, NB * ++ep);

    // P1: per-node root chase + bin key + histogram
    for (int i = tid; i < NN; i += GT) {
        int d = depth[i];
        int r = i;
        for (int s = 0; s < d; ++s) r = pnode2[r].x;   // fixed-point safe at roots
        int K = (r & (NB2 - 1)) * 32 + d * 2 + (cnt_n[i] == 0 ? 1 : 0);
        K_s[i] = K;
        atomicAdd(&bin_cnt[K], 1);
    }
    gbar_f(bar, NB * ++ep);

    // P2: bin scan (orderless base): blocks 0..127, 256 bins each
    if (blockIdx.x < NBINS / NT) {
        int k0 = blockIdx.x * NT + t;
        int v = bin_cnt[k0];
        sh[t] = v;
        __syncthreads();
        for (int ofs = 1; ofs < NT; ofs <<= 1) {
            int x = (t >= ofs) ? sh[t - ofs] : 0;
            __syncthreads();
            sh[t] += x;
            __syncthreads();
        }
        if (t == NT - 1) sbase_sh = atomicAdd(&totals[0], sh[t]);
        __syncthreads();
        int b = sbase_sh + sh[t] - v;
        bin_base[k0] = b;
        bin_cur[k0] = b;
    }
    gbar_f(bar, NB * ++ep);

    // P3: scatter (counting sort) — ONE packed 16B scattered write per node
    for (int i = tid; i < NN; i += GT) {
        int pos = atomicAdd(&bin_cur[K_s[i]], 1);
        int2 pe = pnode2[i];                            // coalesced
        int gr = (isr[i] != 0.f) ? gid[i] : -1;         // coalesced
        nodeinfo[pos] = make_int4(i, cnt_n[i], gr, pe.y);   // scattered 16B
        inv[i] = pos;                                   // coalesced
    }
    gbar_f(bar, NB * ++ep);

    // P4: row_ptr via span scan + orderless base; cnt_n reused as cur
    {
        int base0 = blockIdx.x * SPAN + t * SE;
        int v[SE]; int sum = 0;
        #pragma unroll
        for (int k = 0; k < SE; ++k) { v[k] = nodeinfo[base0 + k].y; sum += v[k]; }
        __syncthreads();
        sh[t] = sum;
        __syncthreads();
        for (int ofs = 1; ofs < NT; ofs <<= 1) {
            int x = (t >= ofs) ? sh[t - ofs] : 0;
            __syncthreads();
            sh[t] += x;
            __syncthreads();
        }
        if (t == NT - 1) sbase_sh = atomicAdd(&totals[16], sh[t]);
        __syncthreads();
        int run = sbase_sh + sh[t] - sum;
        #pragma unroll
        for (int k = 0; k < SE; ++k) { row_ptr[base0 + k] = run; cnt_n[base0 + k] = run; run += v[k]; }
    }
    gbar_f(bar, NB * ++ep);

    // P5: child pass in pos order — only adjc is a scattered write
    for (int pos = tid; pos < NN; pos += GT) {
        int4 ni = nodeinfo[pos];                        // coalesced
        if (ni.w >= 0) {                                // has a parent edge
            int ppn = pnode2[ni.x].x;                   // clean scattered read (hot 8MB)
            int pp  = inv[ppn];                         // clean scattered read (4MB)
            int slot = atomicAdd(&cnt_n[pp], 1);        // cur
            adjc[slot] = pos;                           // scattered 4B write
        }
    }
}

// cooperative MLP phases 1-2 (x pre-staged in xs column `slot`): lane j owns
// hidden units 9j..9j+8 and outputs 5j..5j+4. Result: o[5] + os column.
__device__ __forceinline__ void coop_mlp(int slot, int j, int KN,
                                         const float* xs, float* hs, float* os,
                                         const float* w1, const float* b1,
                                         const float* w2, const float* b2,
                                         float* o)
{
    wsync();                       // xs writes (all lanes) before xs reads
    float acc[9];
    #pragma unroll
    for (int u = 0; u < 9; ++u) { int h = 9*j + u; acc[u] = (h < HID) ? b1[h] : 0.f; }
    #pragma unroll 2
    for (int k = 0; k < KN; ++k) {
        float xk = xs[k * SSTR + slot];
        #pragma unroll
        for (int u = 0; u < 9; ++u) { int h = 9*j + u; if (h < HID) acc[u] += xk * w1[k * HIDP + h]; }
    }
    #pragma unroll
    for (int u = 0; u < 9; ++u) { int h = 9*j + u; if (h < HID) hs[h * SSTR + slot] = leaky(acc[u]); }
    wsync();                       // hs writes before hs reads
    #pragma unroll
    for (int u = 0; u < 5; ++u) o[u] = b2[5*j + u];
    #pragma unroll 2
    for (int k = 0; k < HID; ++k) {
        float hk = hs[k * SSTR + slot];
        #pragma unroll
        for (int u = 0; u < 5; ++u) o[u] += hk * w2[k * REC + 5*j + u];
    }
    #pragma unroll
    for (int u = 0; u < 5; ++u) { o[u] = leaky(o[u]); os[(5*j + u) * SSTR + slot] = o[u]; }
    wsync();                       // os writes before os reads (msg phase)
}

// ---------------- levels: 4 lanes per node, packed nodeinfo, bond by eid ----------------
__global__ __launch_bounds__(NT2) void k_levels(
    const float* __restrict__ atom, const float* __restrict__ bond,
    const int4* __restrict__ nodeinfo, const int* __restrict__ row_ptr,
    const int* __restrict__ adjc,
    const int* __restrict__ bin_base, const int* __restrict__ bin_cnt,
    const float* __restrict__ iw, const float* __restrict__ ib,
    const float* __restrict__ nw1, const float* __restrict__ nb1,
    const float* __restrict__ nw2, const float* __restrict__ nb2,
    const float* __restrict__ l0w1, const float* __restrict__ l0b1,
    const float* __restrict__ l0w2, const float* __restrict__ l0b2,
    float* __restrict__ g, float* __restrict__ msg_s)
{
    __shared__ float lw1[34 * HIDP];     // net_w1  [34][36]
    __shared__ float lw2[HID * REC];     // net_w2  [34][20]
    __shared__ float liw[23 * REC];      // inner_w [23][20]
    __shared__ float zw1[ATOM * HIDP];   // net0_w1 [14][36]
    __shared__ float zw2[HID * REC];     // net0_w2 [34][20]
    __shared__ float lb1[HID], lb2[REC], lbi[INNER], zb1[HID], zb2[REC];
    __shared__ float xs[34 * SSTR];      // x staging   [34][65]
    __shared__ float hs[34 * SSTR];      // hid staging [34][65]
    __shared__ float os[20 * SSTR];      // out staging [20][65]

    const int t = threadIdx.x;
    const int b = blockIdx.x;
    const int slot = t >> 2;             // node-group 0..63
    const int j = t & 3;                 // lane slice 0..3

    for (int idx = t; idx < 34 * HIDP; idx += NT2) {
        int r = idx / HIDP, c = idx - r * HIDP;
        lw1[idx] = (c < HID) ? nw1[r * HID + c] : 0.f;
    }
    for (int idx = t; idx < HID * REC; idx += NT2) { lw2[idx] = nw2[idx]; zw2[idx] = l0w2[idx]; }
    for (int idx = t; idx < 23 * REC; idx += NT2) liw[idx] = iw[idx];
    for (int idx = t; idx < ATOM * HIDP; idx += NT2) {
        int r = idx / HIDP, c = idx - r * HIDP;
        zw1[idx] = (c < HID) ? l0w1[r * HID + c] : 0.f;
    }
    if (t < HID) { lb1[t] = nb1[t]; zb1[t] = l0b1[t]; }
    else if (t >= 64 && t < 64 + REC) { lb2[t - 64] = nb2[t - 64]; zb2[t - 64] = l0b2[t - 64]; }
    if (t >= 96 && t < 96 + INNER) lbi[t - 96] = ib[t - 96];
    __syncthreads();

    for (int d = 15; d >= 0; --d) {
        // ---- internal nodes (bin b*32 + d*2) ----
        {
            int K = b * 32 + d * 2;
            int base = bin_base[K], n0 = bin_cnt[K];
            for (int idx = slot; idx < n0; idx += NGRP) {
                int pos = base + idx;
                int4 ni = nodeinfo[pos];                // {i, n, gr, eid}
                int rp0 = row_ptr[pos];
                // gather: lane j sums msg slice q in [5j,5j+5)
                float s0 = 0.f, s1 = 0.f, s2 = 0.f, s3 = 0.f, s4 = 0.f;
                for (int r = rp0; r < rp0 + ni.y; ++r) {
                    const float* mp = msg_s + (size_t)adjc[r] * REC + 5*j;
                    s0 += mp[0]; s1 += mp[1]; s2 += mp[2]; s3 += mp[3]; s4 += mp[4];
                }
                // stage x = [atom, isum]
                const float* ar = atom + (size_t)ni.x * ATOM;
                #pragma unroll
                for (int u = 0; u < 4; ++u) { int k = 4*j + u; if (k < ATOM) xs[k * SSTR + slot] = ar[k]; }
                xs[(ATOM + 5*j + 0) * SSTR + slot] = s0;
                xs[(ATOM + 5*j + 1) * SSTR + slot] = s1;
                xs[(ATOM + 5*j + 2) * SSTR + slot] = s2;
                xs[(ATOM + 5*j + 3) * SSTR + slot] = s3;
                xs[(ATOM + 5*j + 4) * SSTR + slot] = s4;
                float o[5];
                coop_mlp(slot, j, ATOM + INNER, xs, hs, os, lw1, lb1, lw2, lb2, o);
                if (ni.z >= 0) {
                    #pragma unroll
                    for (int u = 0; u < 5; ++u) atomicAdd(&g[(size_t)ni.z * REC + 5*j + u], o[u]);
                } else {
                    const float* br = bond + (size_t)ni.w * BOND;
                    float b0 = br[0], b1 = br[1], b2 = br[2];
                    float m[5];
                    #pragma unroll
                    for (int u = 0; u < 5; ++u)
                        m[u] = lbi[5*j + u] + b0 * liw[0 * INNER + 5*j + u]
                             + b1 * liw[1 * INNER + 5*j + u] + b2 * liw[2 * INNER + 5*j + u];
                    #pragma unroll 2
                    for (int k = 0; k < REC; ++k) {
                        float ok = os[k * SSTR + slot];
                        #pragma unroll
                        for (int u = 0; u < 5; ++u) m[u] += ok * liw[(BOND + k) * INNER + 5*j + u];
                    }
                    #pragma unroll
                    for (int u = 0; u < 5; ++u) msg_s[(size_t)pos * REC + 5*j + u] = leaky(m[u]);
                }
            }
        }
        // ---- leaves (bin b*32 + d*2 + 1) ----
        {
            int K = b * 32 + d * 2 + 1;
            int base = bin_base[K], n1 = bin_cnt[K];
            for (int idx = slot; idx < n1; idx += NGRP) {
                int pos = base + idx;
                int4 ni = nodeinfo[pos];
                const float* ar = atom + (size_t)ni.x * ATOM;
                #pragma unroll
                for (int u = 0; u < 4; ++u) { int k = 4*j + u; if (k < ATOM) xs[k * SSTR + slot] = ar[k]; }
                float o[5];
                coop_mlp(slot, j, ATOM, xs, hs, os, zw1, zb1, zw2, zb2, o);
                if (ni.z >= 0) {
                    #pragma unroll
                    for (int u = 0; u < 5; ++u) atomicAdd(&g[(size_t)ni.z * REC + 5*j + u], o[u]);
                } else {
                    const float* br = bond + (size_t)ni.w * BOND;
                    float b0 = br[0], b1 = br[1], b2 = br[2];
                    float m[5];
                    #pragma unroll
                    for (int u = 0; u < 5; ++u)
                        m[u] = lbi[5*j + u] + b0 * liw[0 * INNER + 5*j + u]
                             + b1 * liw[1 * INNER + 5*j + u] + b2 * liw[2 * INNER + 5*j + u];
                    #pragma unroll 2
                    for (int k = 0; k < REC; ++k) {
                        float ok = os[k * SSTR + slot];
                        #pragma unroll
                        for (int u = 0; u < 5; ++u) m[u] += ok * liw[(BOND + k) * INNER + 5*j + u];
                    }
                    #pragma unroll
                    for (int u = 0; u < 5; ++u) msg_s[(size_t)pos * REC + 5*j + u] = leaky(m[u]);
                }
            }
        }
        // block-local level barrier (msg producer->consumer across waves)
        __threadfence_block();
        __syncthreads();
    }
}

// ---------------- readout ----------------
__global__ void k_out(const float* __restrict__ g,
                      const float* __restrict__ w1, const float* __restrict__ b1,
                      const float* __restrict__ w2, const float* __restrict__ b2,
                      float* __restrict__ out) {
    int t = blockIdx.x * 256 + threadIdx.x;
    if (t >= NG) return;
    const float* gv = g + (size_t)t * REC;
    float gl[REC];
    #pragma unroll
    for (int k = 0; k < REC; ++k) gl[k] = gv[k];
    float acc = b2[0];
    for (int j = 0; j < OHID; ++j) {
        float s = b1[j];
        #pragma unroll
        for (int k = 0; k < REC; ++k) s += gl[k] * w1[k * OHID + j];
        acc += tanhf(s) * w2[j];
    }
    out[t] = acc;
}

extern "C" void kernel_launch(void* const* d_in, const int* in_sizes, int n_in,
                              void* d_out, int out_size, void* d_ws, size_t ws_size,
                              hipStream_t stream) {
    const float* atom    = (const float*)d_in[0];
    const float* bond    = (const float*)d_in[1];
    const int*   parent  = (const int*)d_in[2];
    const int*   child   = (const int*)d_in[3];
    const int*   depth   = (const int*)d_in[4];
    const int*   gid     = (const int*)d_in[5];
    const float* isr     = (const float*)d_in[6];
    const float* inner_w = (const float*)d_in[7];
    const float* inner_b = (const float*)d_in[8];
    const float* net_w1  = (const float*)d_in[9];
    const float* net_b1  = (const float*)d_in[10];
    const float* net_w2  = (const float*)d_in[11];
    const float* net_b2  = (const float*)d_in[12];
    const float* net0_w1 = (const float*)d_in[13];
    const float* net0_b1 = (const float*)d_in[14];
    const float* net0_w2 = (const float*)d_in[15];
    const float* net0_b2 = (const float*)d_in[16];
    const float* out_w1  = (const float*)d_in[17];
    const float* out_b1  = (const float*)d_in[18];
    const float* out_w2  = (const float*)d_in[19];
    const float* out_b2  = (const float*)d_in[20];
    float* out = (float*)d_out;

    char* ws = (char*)d_ws;
    size_t o = 0;
    float* msg_s    = (float*)(ws + o);  o += (size_t)NN * REC * 4;    // 83.9 MB
    int4* nodeinfo  = (int4*)(ws + o);   o += (size_t)NN * 16;         // 16.8 MB
    float* g        = (float*)(ws + o);  o += (size_t)NG * REC * 4;    // 1.3 MB
    int2* pnode2    = (int2*)(ws + o);   o += (size_t)NN * 8;          // 8.4 MB
    int* adjc       = (int*)(ws + o);    o += (size_t)NE * 4;          // 3.9 MB
    int* cnt_n      = (int*)(ws + o);    o += (size_t)NN * 4;          // 4.2 MB (also cur)
    int* inv        = (int*)(ws + o);    o += (size_t)NN * 4;          // 4.2 MB
    int* K_s        = (int*)(ws + o);    o += (size_t)NN * 4;          // 4.2 MB
    int* row_ptr    = (int*)(ws + o);    o += (size_t)NN * 4;          // 4.2 MB
    int* bin_cnt    = (int*)(ws + o);    o += (size_t)NBINS * 4;       // 128 KB
    int* bin_base   = (int*)(ws + o);    o += (size_t)NBINS * 4;       // 128 KB
    int* bin_cur    = (int*)(ws + o);    o += (size_t)NBINS * 4;       // 128 KB
    int* totals     = (int*)(ws + o);    o += 32 * 4;
    int* bars       = (int*)(ws + o);    o += 32 * 4;
    // total ~131 MB

    k_pre<<<1024, 256, 0, stream>>>(cnt_n, pnode2, g, bin_cnt, totals, bars);
    k_prep<<<NB, NT, 0, stream>>>(parent, child, depth, gid, isr,
                                  cnt_n, pnode2, inv, K_s, nodeinfo, row_ptr,
                                  adjc, bin_cnt, bin_base, bin_cur, totals, bars);
    k_levels<<<NB2, NT2, 0, stream>>>(atom, bond, nodeinfo, row_ptr, adjc,
                                      bin_base, bin_cnt,
                                      inner_w, inner_b, net_w1, net_b1, net_w2, net_b2,
                                      net0_w1, net0_b1, net0_w2, net0_b2,
                                      g, msg_s);
    k_out<<<(NG + 255) / 256, 256, 0, stream>>>(g, out_w1, out_b1, out_w2, out_b2, out);
}

// Round 21
// 889.117 us; speedup vs baseline: 1.9039x; 1.0704x over previous
//
#include <hip/hip_runtime.h>

#define ATOM  14
#define BOND  3
#define INNER 20
#define HID   34
#define HIDP  36             // HID padded for LDS rows
#define REC   20
#define OHID  25
#define NN    1048576
#define NE    983040
#define NG    16384

#define NB    512            // prep persistent grid
#define NT    256
#define GT    (NB*NT)        // 131072
#define NIT   (NN/GT)        // 8 strided iterations in node phases

#define NB2   1024           // level blocks (independent tree-bins)
#define NT2   256            // 4 waves
#define NGRP  (NT2/4)        // 64 node-groups (4 lanes each) per block
#define SSTR  (NGRP+1)       // 65: stride-padded staging
#define NBINS (NB2*32)       // bin = blk*32 + depth*2 + isLeaf

__device__ __forceinline__ float leaky(float x) { return x >= 0.f ? x : 0.01f * x; }

__device__ __forceinline__ void wsync() {
    __builtin_amdgcn_wave_barrier();
    __builtin_amdgcn_sched_barrier(0);
}

// grid-wide barrier for prep only: device-scope fences (cross-XCD safe)
__device__ __forceinline__ void gbar_f(int* bar, int goal) {
    __syncthreads();
    if (threadIdx.x == 0) {
        __threadfence();
        __hip_atomic_fetch_add(bar, 1, __ATOMIC_RELEASE, __HIP_MEMORY_SCOPE_AGENT);
        while (__hip_atomic_load(bar, __ATOMIC_RELAXED, __HIP_MEMORY_SCOPE_AGENT) < goal)
            __builtin_amdgcn_s_sleep(32);
        __threadfence();
    }
    __syncthreads();
}

__global__ void k_pre(int* cnt_n, int2* pnode2, float* g, int* bin_cnt, int* totals, int* bars) {
    int tid = blockIdx.x * 256 + threadIdx.x;          // 262144 threads
    for (int i = tid; i < NN; i += 262144) { cnt_n[i] = 0; pnode2[i] = make_int2(i, -1); }
    for (int i = tid; i < NG * REC; i += 262144) g[i] = 0.f;
    for (int i = tid; i < NBINS; i += 262144) bin_cnt[i] = 0;
    if (tid == 0) { totals[0] = 0; totals[16] = 0; }
    if (tid == 1) for (int k = 0; k < 32; ++k) bars[k] = 0;
}

// ---------------- prep: counts+rank, root-chase, sort+row-alloc, child pass ----------------
__global__ __launch_bounds__(NT) void k_prep(
    const int* __restrict__ parent, const int* __restrict__ child,
    const int* __restrict__ depth, const int* __restrict__ gid,
    const float* __restrict__ isr,
    int* cnt_n, int2* pnode2, int* K_s,
    int4* nodeinfo, int* row_n, int* adjc,
    int* bin_cnt, int* bin_base, int* bin_cur,
    int* totals, int* bar)
{
    __shared__ int sh[NT];
    __shared__ int sbase_sh;
    const int t = threadIdx.x;
    const int tid = blockIdx.x * NT + t;
    int ep = 0;

    // P0: child counts (returns rank) + packed (parent, rank|eid) per child
    for (int e = tid; e < NE; e += GT) {
        int p = parent[e];
        int r = atomicAdd(&cnt_n[p], 1);
        pnode2[child[e]] = make_int2(p, (r << 20) | e);
    }
    gbar_f(bar, NB * ++ep);

    // P1: per-node root chase + bin key + histogram
    for (int i = tid; i < NN; i += GT) {
        int d = depth[i];
        int r = i;
        for (int s = 0; s < d; ++s) r = pnode2[r].x;   // fixed-point safe at roots
        int K = (r & (NB2 - 1)) * 32 + d * 2 + (cnt_n[i] == 0 ? 1 : 0);
        K_s[i] = K;
        atomicAdd(&bin_cnt[K], 1);
    }
    gbar_f(bar, NB * ++ep);

    // P2: bin scan (orderless base): blocks 0..127, 256 bins each
    if (blockIdx.x < NBINS / NT) {
        int k0 = blockIdx.x * NT + t;
        int v = bin_cnt[k0];
        sh[t] = v;
        __syncthreads();
        for (int ofs = 1; ofs < NT; ofs <<= 1) {
            int x = (t >= ofs) ? sh[t - ofs] : 0;
            __syncthreads();
            sh[t] += x;
            __syncthreads();
        }
        if (t == NT - 1) sbase_sh = atomicAdd(&totals[0], sh[t]);
        __syncthreads();
        int b = sbase_sh + sh[t] - v;
        bin_base[k0] = b;
        bin_cur[k0] = b;
    }
    gbar_f(bar, NB * ++ep);

    // P3: counting-sort scatter + fused orderless row allocation.
    // One packed 16B scattered write per node; row_n coalesced.
    for (int k = 0; k < NIT; ++k) {
        int i = tid + k * GT;
        int cn = cnt_n[i];
        __syncthreads();                     // protect sh reuse
        sh[t] = cn;
        __syncthreads();
        for (int ofs = 1; ofs < NT; ofs <<= 1) {
            int x = (t >= ofs) ? sh[t - ofs] : 0;
            __syncthreads();
            sh[t] += x;
            __syncthreads();
        }
        if (t == NT - 1) sbase_sh = atomicAdd(&totals[16], sh[t]);
        __syncthreads();
        int row = sbase_sh + sh[t] - cn;     // exclusive prefix + block base
        int pos = atomicAdd(&bin_cur[K_s[i]], 1);
        int2 pe = pnode2[i];                 // coalesced
        int gr = (isr[i] != 0.f) ? gid[i] : -1;   // coalesced
        nodeinfo[pos] = make_int4(i, pe.y, gr, (row << 12) | cn);  // scattered 16B
        row_n[i] = row;                      // coalesced
    }
    gbar_f(bar, NB * ++ep);

    // P4: child pass in pos order — no atomics; only adjc is a scattered write
    for (int pos = tid; pos < NN; pos += GT) {
        int4 ni = nodeinfo[pos];             // coalesced
        if (ni.z < 0) {                      // non-root => has a parent edge
            int ppn = pnode2[ni.x].x;        // scattered read (hot 8MB)
            int rank = ((unsigned)ni.y) >> 20;
            int slot = row_n[ppn] + rank;    // scattered read (4MB)
            adjc[slot] = pos;                // scattered 4B write
        }
    }
}

// cooperative MLP phases 1-2 (x pre-staged in xs column `slot`): lane j owns
// hidden units 9j..9j+8 and outputs 5j..5j+4. Result: o[5] + os column.
__device__ __forceinline__ void coop_mlp(int slot, int j, int KN,
                                         const float* xs, float* hs, float* os,
                                         const float* w1, const float* b1,
                                         const float* w2, const float* b2,
                                         float* o)
{
    wsync();                       // xs writes (all lanes) before xs reads
    float acc[9];
    #pragma unroll
    for (int u = 0; u < 9; ++u) { int h = 9*j + u; acc[u] = (h < HID) ? b1[h] : 0.f; }
    #pragma unroll 2
    for (int k = 0; k < KN; ++k) {
        float xk = xs[k * SSTR + slot];
        #pragma unroll
        for (int u = 0; u < 9; ++u) { int h = 9*j + u; if (h < HID) acc[u] += xk * w1[k * HIDP + h]; }
    }
    #pragma unroll
    for (int u = 0; u < 9; ++u) { int h = 9*j + u; if (h < HID) hs[h * SSTR + slot] = leaky(acc[u]); }
    wsync();                       // hs writes before hs reads
    #pragma unroll
    for (int u = 0; u < 5; ++u) o[u] = b2[5*j + u];
    #pragma unroll 2
    for (int k = 0; k < HID; ++k) {
        float hk = hs[k * SSTR + slot];
        #pragma unroll
        for (int u = 0; u < 5; ++u) o[u] += hk * w2[k * REC + 5*j + u];
    }
    #pragma unroll
    for (int u = 0; u < 5; ++u) { o[u] = leaky(o[u]); os[(5*j + u) * SSTR + slot] = o[u]; }
    wsync();                       // os writes before os reads (msg phase)
}

// ---------------- levels: 4 lanes per node, packed nodeinfo, bond by eid ----------------
__global__ __launch_bounds__(NT2) void k_levels(
    const float* __restrict__ atom, const float* __restrict__ bond,
    const int4* __restrict__ nodeinfo, const int* __restrict__ adjc,
    const int* __restrict__ bin_base, const int* __restrict__ bin_cnt,
    const float* __restrict__ iw, const float* __restrict__ ib,
    const float* __restrict__ nw1, const float* __restrict__ nb1,
    const float* __restrict__ nw2, const float* __restrict__ nb2,
    const float* __restrict__ l0w1, const float* __restrict__ l0b1,
    const float* __restrict__ l0w2, const float* __restrict__ l0b2,
    float* __restrict__ g, float* __restrict__ msg_s)
{
    __shared__ float lw1[34 * HIDP];     // net_w1  [34][36]
    __shared__ float lw2[HID * REC];     // net_w2  [34][20]
    __shared__ float liw[23 * REC];      // inner_w [23][20]
    __shared__ float zw1[ATOM * HIDP];   // net0_w1 [14][36]
    __shared__ float zw2[HID * REC];     // net0_w2 [34][20]
    __shared__ float lb1[HID], lb2[REC], lbi[INNER], zb1[HID], zb2[REC];
    __shared__ float xs[34 * SSTR];      // x staging   [34][65]
    __shared__ float hs[34 * SSTR];      // hid staging [34][65]
    __shared__ float os[20 * SSTR];      // out staging [20][65]

    const int t = threadIdx.x;
    const int b = blockIdx.x;
    const int slot = t >> 2;             // node-group 0..63
    const int j = t & 3;                 // lane slice 0..3

    for (int idx = t; idx < 34 * HIDP; idx += NT2) {
        int r = idx / HIDP, c = idx - r * HIDP;
        lw1[idx] = (c < HID) ? nw1[r * HID + c] : 0.f;
    }
    for (int idx = t; idx < HID * REC; idx += NT2) { lw2[idx] = nw2[idx]; zw2[idx] = l0w2[idx]; }
    for (int idx = t; idx < 23 * REC; idx += NT2) liw[idx] = iw[idx];
    for (int idx = t; idx < ATOM * HIDP; idx += NT2) {
        int r = idx / HIDP, c = idx - r * HIDP;
        zw1[idx] = (c < HID) ? l0w1[r * HID + c] : 0.f;
    }
    if (t < HID) { lb1[t] = nb1[t]; zb1[t] = l0b1[t]; }
    else if (t >= 64 && t < 64 + REC) { lb2[t - 64] = nb2[t - 64]; zb2[t - 64] = l0b2[t - 64]; }
    if (t >= 96 && t < 96 + INNER) lbi[t - 96] = ib[t - 96];
    __syncthreads();

    for (int d = 15; d >= 0; --d) {
        // ---- internal nodes (bin b*32 + d*2) ----
        {
            int K = b * 32 + d * 2;
            int base = bin_base[K], n0 = bin_cnt[K];
            for (int idx = slot; idx < n0; idx += NGRP) {
                int pos = base + idx;
                int4 ni = nodeinfo[pos];                // {i, rank|eid, gr, row|n}
                int n   = ni.w & 0xFFF;
                int rp0 = ((unsigned)ni.w) >> 12;
                // gather: lane j sums msg slice q in [5j,5j+5)
                float s0 = 0.f, s1 = 0.f, s2 = 0.f, s3 = 0.f, s4 = 0.f;
                for (int r = rp0; r < rp0 + n; ++r) {
                    const float* mp = msg_s + (size_t)adjc[r] * REC + 5*j;
                    s0 += mp[0]; s1 += mp[1]; s2 += mp[2]; s3 += mp[3]; s4 += mp[4];
                }
                // stage x = [atom, isum]
                const float* ar = atom + (size_t)ni.x * ATOM;
                #pragma unroll
                for (int u = 0; u < 4; ++u) { int k = 4*j + u; if (k < ATOM) xs[k * SSTR + slot] = ar[k]; }
                xs[(ATOM + 5*j + 0) * SSTR + slot] = s0;
                xs[(ATOM + 5*j + 1) * SSTR + slot] = s1;
                xs[(ATOM + 5*j + 2) * SSTR + slot] = s2;
                xs[(ATOM + 5*j + 3) * SSTR + slot] = s3;
                xs[(ATOM + 5*j + 4) * SSTR + slot] = s4;
                float o[5];
                coop_mlp(slot, j, ATOM + INNER, xs, hs, os, lw1, lb1, lw2, lb2, o);
                if (ni.z >= 0) {
                    #pragma unroll
                    for (int u = 0; u < 5; ++u) atomicAdd(&g[(size_t)ni.z * REC + 5*j + u], o[u]);
                } else {
                    const float* br = bond + (size_t)(ni.y & 0xFFFFF) * BOND;
                    float b0 = br[0], b1 = br[1], b2 = br[2];
                    float m[5];
                    #pragma unroll
                    for (int u = 0; u < 5; ++u)
                        m[u] = lbi[5*j + u] + b0 * liw[0 * INNER + 5*j + u]
                             + b1 * liw[1 * INNER + 5*j + u] + b2 * liw[2 * INNER + 5*j + u];
                    #pragma unroll 2
                    for (int k = 0; k < REC; ++k) {
                        float ok = os[k * SSTR + slot];
                        #pragma unroll
                        for (int u = 0; u < 5; ++u) m[u] += ok * liw[(BOND + k) * INNER + 5*j + u];
                    }
                    #pragma unroll
                    for (int u = 0; u < 5; ++u) msg_s[(size_t)pos * REC + 5*j + u] = leaky(m[u]);
                }
            }
        }
        // ---- leaves (bin b*32 + d*2 + 1) ----
        {
            int K = b * 32 + d * 2 + 1;
            int base = bin_base[K], n1 = bin_cnt[K];
            for (int idx = slot; idx < n1; idx += NGRP) {
                int pos = base + idx;
                int4 ni = nodeinfo[pos];
                const float* ar = atom + (size_t)ni.x * ATOM;
                #pragma unroll
                for (int u = 0; u < 4; ++u) { int k = 4*j + u; if (k < ATOM) xs[k * SSTR + slot] = ar[k]; }
                float o[5];
                coop_mlp(slot, j, ATOM, xs, hs, os, zw1, zb1, zw2, zb2, o);
                if (ni.z >= 0) {
                    #pragma unroll
                    for (int u = 0; u < 5; ++u) atomicAdd(&g[(size_t)ni.z * REC + 5*j + u], o[u]);
                } else {
                    const float* br = bond + (size_t)(ni.y & 0xFFFFF) * BOND;
                    float b0 = br[0], b1 = br[1], b2 = br[2];
                    float m[5];
                    #pragma unroll
                    for (int u = 0; u < 5; ++u)
                        m[u] = lbi[5*j + u] + b0 * liw[0 * INNER + 5*j + u]
                             + b1 * liw[1 * INNER + 5*j + u] + b2 * liw[2 * INNER + 5*j + u];
                    #pragma unroll 2
                    for (int k = 0; k < REC; ++k) {
                        float ok = os[k * SSTR + slot];
                        #pragma unroll
                        for (int u = 0; u < 5; ++u) m[u] += ok * liw[(BOND + k) * INNER + 5*j + u];
                    }
                    #pragma unroll
                    for (int u = 0; u < 5; ++u) msg_s[(size_t)pos * REC + 5*j + u] = leaky(m[u]);
                }
            }
        }
        // block-local level barrier (msg producer->consumer across waves)
        __threadfence_block();
        __syncthreads();
    }
}

// ---------------- readout ----------------
__global__ void k_out(const float* __restrict__ g,
                      const float* __restrict__ w1, const float* __restrict__ b1,
                      const float* __restrict__ w2, const float* __restrict__ b2,
                      float* __restrict__ out) {
    int t = blockIdx.x * 256 + threadIdx.x;
    if (t >= NG) return;
    const float* gv = g + (size_t)t * REC;
    float gl[REC];
    #pragma unroll
    for (int k = 0; k < REC; ++k) gl[k] = gv[k];
    float acc = b2[0];
    for (int j = 0; j < OHID; ++j) {
        float s = b1[j];
        #pragma unroll
        for (int k = 0; k < REC; ++k) s += gl[k] * w1[k * OHID + j];
        acc += tanhf(s) * w2[j];
    }
    out[t] = acc;
}

extern "C" void kernel_launch(void* const* d_in, const int* in_sizes, int n_in,
                              void* d_out, int out_size, void* d_ws, size_t ws_size,
                              hipStream_t stream) {
    const float* atom    = (const float*)d_in[0];
    const float* bond    = (const float*)d_in[1];
    const int*   parent  = (const int*)d_in[2];
    const int*   child   = (const int*)d_in[3];
    const int*   depth   = (const int*)d_in[4];
    const int*   gid     = (const int*)d_in[5];
    const float* isr     = (const float*)d_in[6];
    const float* inner_w = (const float*)d_in[7];
    const float* inner_b = (const float*)d_in[8];
    const float* net_w1  = (const float*)d_in[9];
    const float* net_b1  = (const float*)d_in[10];
    const float* net_w2  = (const float*)d_in[11];
    const float* net_b2  = (const float*)d_in[12];
    const float* net0_w1 = (const float*)d_in[13];
    const float* net0_b1 = (const float*)d_in[14];
    const float* net0_w2 = (const float*)d_in[15];
    const float* net0_b2 = (const float*)d_in[16];
    const float* out_w1  = (const float*)d_in[17];
    const float* out_b1  = (const float*)d_in[18];
    const float* out_w2  = (const float*)d_in[19];
    const float* out_b2  = (const float*)d_in[20];
    float* out = (float*)d_out;

    char* ws = (char*)d_ws;
    size_t o = 0;
    float* msg_s    = (float*)(ws + o);  o += (size_t)NN * REC * 4;    // 83.9 MB
    int4* nodeinfo  = (int4*)(ws + o);   o += (size_t)NN * 16;         // 16.8 MB
    float* g        = (float*)(ws + o);  o += (size_t)NG * REC * 4;    // 1.3 MB
    int2* pnode2    = (int2*)(ws + o);   o += (size_t)NN * 8;          // 8.4 MB
    int* adjc       = (int*)(ws + o);    o += (size_t)NE * 4;          // 3.9 MB
    int* cnt_n      = (int*)(ws + o);    o += (size_t)NN * 4;          // 4.2 MB
    int* row_n      = (int*)(ws + o);    o += (size_t)NN * 4;          // 4.2 MB
    int* K_s        = (int*)(ws + o);    o += (size_t)NN * 4;          // 4.2 MB
    int* bin_cnt    = (int*)(ws + o);    o += (size_t)NBINS * 4;       // 128 KB
    int* bin_base   = (int*)(ws + o);    o += (size_t)NBINS * 4;       // 128 KB
    int* bin_cur    = (int*)(ws + o);    o += (size_t)NBINS * 4;       // 128 KB
    int* totals     = (int*)(ws + o);    o += 32 * 4;
    int* bars       = (int*)(ws + o);    o += 32 * 4;
    // total ~127 MB

    k_pre<<<1024, 256, 0, stream>>>(cnt_n, pnode2, g, bin_cnt, totals, bars);
    k_prep<<<NB, NT, 0, stream>>>(parent, child, depth, gid, isr,
                                  cnt_n, pnode2, K_s, nodeinfo, row_n,
                                  adjc, bin_cnt, bin_base, bin_cur, totals, bars);
    k_levels<<<NB2, NT2, 0, stream>>>(atom, bond, nodeinfo, adjc,
                                      bin_base, bin_cnt,
                                      inner_w, inner_b, net_w1, net_b1, net_w2, net_b2,
                                      net0_w1, net0_b1, net0_w2, net0_b2,
                                      g, msg_s);
    k_out<<<(NG + 255) / 256, 256, 0, stream>>>(g, out_w1, out_b1, out_w2, out_b2, out);
}